// Round 6
// baseline (10830.997 us; speedup 1.0000x reference)
//
#include <hip/hip_runtime.h>
#include <cstdint>
#include <cstddef>
#include <cstring>

#define LSEQ 512
#define BATCH 64
#define DIM 256
#define HID 256
#define NTAG 11

// ---------------- input GEMM (+embedding gather, +bias) ----------------
// Gin layout: [dir][t_local][b][pos(n)] where for row n = g*256+e:
//   pos = (e>>1)*8 + (e&1)*4 + g   (matches lstm_rec's tid->row mapping, so
//   each wave's per-step Gin read is 256B contiguous)
__global__ void __launch_bounds__(256) gemm_in(
    const int* __restrict__ sent, const float* __restrict__ emb,
    const float* __restrict__ Wf, const float* __restrict__ bf,
    const float* __restrict__ Wb, const float* __restrict__ bb,
    float* __restrict__ Gin, int t0, int CT)
{
    const int mt = blockIdx.x, nt = blockIdx.y, dir = blockIdx.z;
    const float* __restrict__ W    = dir ? Wb : Wf;
    const float* __restrict__ bias = dir ? bb : bf;
    const int tid = threadIdx.x;
    const int tx = tid & 15, ty = tid >> 4;

    __shared__ float As[128][36];
    __shared__ float Bs[128][36];

    const float* arow[4];
    const float* brow[4];
#pragma unroll
    for (int j = 0; j < 4; j++) {
        int v  = j * 256 + tid;
        int mi = v >> 3;
        int m_g = mt * 128 + mi;
        int b = m_g & 63, tl = m_g >> 6;
        int tg = t0 + tl;
        int tt = dir ? (LSEQ - 1 - tg) : tg;
        int tok = sent[b * LSEQ + tt];
        arow[j] = emb + (size_t)tok * DIM;
        brow[j] = W + (size_t)(nt * 128 + mi) * DIM;
    }

    float acc[8][8];
#pragma unroll
    for (int i = 0; i < 8; i++)
#pragma unroll
        for (int j = 0; j < 8; j++) acc[i][j] = 0.f;

    for (int ki = 0; ki < 8; ki++) {
        const int k0 = ki * 32;
        __syncthreads();
#pragma unroll
        for (int j = 0; j < 4; j++) {
            int v  = j * 256 + tid;
            int mi = v >> 3, k4 = v & 7;
            float4 av = *(const float4*)(arow[j] + k0 + k4 * 4);
            float4 bv = *(const float4*)(brow[j] + k0 + k4 * 4);
            *(float4*)&As[mi][k4 * 4] = av;
            *(float4*)&Bs[mi][k4 * 4] = bv;
        }
        __syncthreads();
#pragma unroll
        for (int k = 0; k < 32; k++) {
            float a[8], bv[8];
#pragma unroll
            for (int i = 0; i < 8; i++) a[i] = As[ty + 16 * i][k];
#pragma unroll
            for (int j = 0; j < 8; j++) bv[j] = Bs[tx + 16 * j][k];
#pragma unroll
            for (int i = 0; i < 8; i++)
#pragma unroll
                for (int j = 0; j < 8; j++) acc[i][j] = fmaf(a[i], bv[j], acc[i][j]);
        }
    }
#pragma unroll
    for (int i = 0; i < 8; i++) {
        int m_g = mt * 128 + ty + 16 * i;
        int b = m_g & 63, tl = m_g >> 6;
        size_t base = ((size_t)(dir * CT + tl) * 64 + b) * 1024;
#pragma unroll
        for (int j = 0; j < 8; j++) {
            int n = nt * 128 + tx + 16 * j;
            int g = n >> 8, e = n & 255;
            int pos = ((e >> 1) << 3) + ((e & 1) << 2) + g;
            Gin[base + pos] = acc[i][j] + bias[n];
        }
    }
}

// ---------------- LSTM recurrence: one 1024-thread WG per (dir,batch) ----
// 128 WGs; each holds the ENTIRE 1MB W_hh slice-set in registers
// (256 VGPRs/thread of weights). h ping-pongs in LDS — NO cross-WG
// communication, ONE __syncthreads per step.
// Thread (ro=tid>>3, kq=tid&7): slot m -> row (m&3)*256 + ro*2 + (m>>2),
// k-chunk [kq*32, kq*32+32). Reduction over kq via shfl_xor tree; final
// lane kq holds row_of(ro,kq) = its own tid-position (Gin laid out to match).
// 2 WGs can never co-reside (VGPRs >256) => dispatcher spreads 1/CU.
__global__ void __launch_bounds__(1024, 1) lstm_rec(
    const float* __restrict__ Gin,
    const float* __restrict__ Whh_f, const float* __restrict__ Whh_b,
    const float* __restrict__ h0, const float* __restrict__ c0,
    float* __restrict__ hs, float* __restrict__ cbuf, int t0, int CT)
{
    const int u = blockIdx.x;
    const int dir = u >> 6, b = u & 63;
    const int tid = threadIdx.x;
    const int lane = tid & 63;
    const int ro = tid >> 3, kq = tid & 7;
    const int e = ro * 2 + (kq >> 2);   // the hidden elem this lane activates
    const float* __restrict__ Whh = dir ? Whh_b : Whh_f;

    __shared__ float hsh[2][260];       // ping-pong h

    // weights: 64 float4 = 256 VGPRs
    float4 wreg[64];
#pragma unroll
    for (int m = 0; m < 8; m++) {
        const int row = ((m & 3) << 8) + (ro << 1) + (m >> 2);
        const float4* wp = (const float4*)(Whh + (size_t)row * HID + kq * 32);
#pragma unroll
        for (int i = 0; i < 8; i++) wreg[m * 8 + i] = wp[i];
    }

    // c init (all 4 redundant lanes of an elem keep identical c)
    float c;
    {
        const float* csrc = (t0 == 0) ? c0 : cbuf;
        c = csrc[((size_t)dir * BATCH + b) * HID + e];
    }
    // h init into LDS slot with parity of (t0-1)
    {
        const int slot = (t0 + 1) & 1;
        if (tid < 64) {
            float4 hv;
            if (t0 == 0) {
                hv = ((const float4*)(h0 + ((size_t)dir * BATCH + b) * HID))[tid];
            } else {
                const int tprev = t0 - 1;
                const int t_orig = dir ? (LSEQ - 1 - tprev) : tprev;
                hv = ((const float4*)(hs + ((size_t)(dir * LSEQ + t_orig) * BATCH + b) * HID))[tid];
            }
            ((float4*)&hsh[slot][0])[tid] = hv;
        }
    }
    __syncthreads();

    const float* __restrict__ gin_base =
        Gin + ((size_t)(dir * CT) * 64 + b) * 1024 + tid;
    float gin_cur = *gin_base;   // t_local = 0

    for (int t = t0; t < t0 + CT; t++) {
        const int rslot = (t + 1) & 1, wslot = t & 1;

        // prefetch Gin for t+1 (off the critical path)
        int tln = t + 1 - t0; if (tln >= CT) tln = CT - 1;
        const float gin_nxt = gin_base[(size_t)tln * 65536];

        // ---- GEMV: 8 rows x 32-k per thread, h from LDS (broadcast groups) ----
        const float4* hsld = (const float4*)&hsh[rslot][0];
        float p[8] = {0.f, 0.f, 0.f, 0.f, 0.f, 0.f, 0.f, 0.f};
#pragma unroll
        for (int i = 0; i < 8; i++) {
            const float4 hv = hsld[kq * 8 + i];
#pragma unroll
            for (int m = 0; m < 8; m++) {
                const float4 wv = wreg[m * 8 + i];
                p[m] = fmaf(wv.x, hv.x, p[m]);
                p[m] = fmaf(wv.y, hv.y, p[m]);
                p[m] = fmaf(wv.z, hv.z, p[m]);
                p[m] = fmaf(wv.w, hv.w, p[m]);
            }
        }

        // ---- reduce over kq (8 lanes) — value-select halving, no dyn idx ----
        const bool u4 = (kq & 4) != 0;
        float q[4];
#pragma unroll
        for (int i = 0; i < 4; i++) {
            const float mine = u4 ? p[4 + i] : p[i];
            const float give = u4 ? p[i] : p[4 + i];
            q[i] = mine + __shfl_xor(give, 4, 64);
        }
        const bool u2 = (kq & 2) != 0;
        float r2[2];
#pragma unroll
        for (int i = 0; i < 2; i++) {
            const float mine = u2 ? q[2 + i] : q[i];
            const float give = u2 ? q[i] : q[2 + i];
            r2[i] = mine + __shfl_xor(give, 2, 64);
        }
        const bool u1 = (kq & 1) != 0;
        {
            const float mine = u1 ? r2[1] : r2[0];
            const float give = u1 ? r2[0] : r2[1];
            r2[0] = mine + __shfl_xor(give, 1, 64);
        }
        const float v = r2[0] + gin_cur;   // full preact for row_of(ro,kq)
        gin_cur = gin_nxt;

        // ---- gather the 4 gates of elem e (same 8-lane group) ----
        const int lb = (lane & 0x38) + (kq & 4);
        const float gi_ = __shfl(v, lb + 0, 64);
        const float gf_ = __shfl(v, lb + 1, 64);
        const float gg_ = __shfl(v, lb + 2, 64);
        const float go_ = __shfl(v, lb + 3, 64);
        const float ig = 1.f / (1.f + expf(-gi_));
        const float fg = 1.f / (1.f + expf(-gf_));
        const float og = 1.f / (1.f + expf(-go_));
        c = fg * c + ig * tanhf(gg_);
        const float h = og * tanhf(c);

        if ((kq & 3) == 0) {
            hsh[wslot][e] = h;
            const int t_orig = dir ? (LSEQ - 1 - t) : t;
            hs[((size_t)(dir * LSEQ + t_orig) * BATCH + b) * HID + e] = h;
        }
        __syncthreads();
    }
    if ((kq & 3) == 0)
        cbuf[((size_t)dir * BATCH + b) * HID + e] = c;
}

// ---------------- output projection: logits[b][t][11] ----------------
__global__ void __launch_bounds__(256) logits_k(
    const float* __restrict__ hs, const float* __restrict__ Wout,
    const float* __restrict__ bout, float* __restrict__ logits)
{
    const int tid = threadIdx.x;
    const int rt = tid >> 4, tg = tid & 15;
    __shared__ float hrow[16][516];
    __shared__ float Wl[NTAG][516];
    const int rbase = blockIdx.x * 16;

#pragma unroll
    for (int i = 0; i < 8; i++) {
        int u  = tid + i * 256;
        int rr = u >> 7, c4 = u & 127;
        int r_g = rbase + rr;
        int b = r_g >> 9, t = r_g & 511;
        int d = (c4 >= 64) ? 1 : 0, k4 = c4 & 63;
        float4 hv = ((const float4*)hs)[(((size_t)d * LSEQ + t) * BATCH + b) * 64 + k4];
        *(float4*)&hrow[rr][c4 * 4] = hv;
    }
    for (int u = tid; u < NTAG * 128; u += 256) {
        int row = u >> 7, c4 = u & 127;
        float4 wv = ((const float4*)Wout)[(size_t)row * 128 + c4];
        *(float4*)&Wl[row][c4 * 4] = wv;
    }
    __syncthreads();

    if (tg < NTAG) {
        const float4* hp = (const float4*)&hrow[rt][0];
        const float4* wp = (const float4*)&Wl[tg][0];
        float acc = 0.f;
#pragma unroll 4
        for (int k = 0; k < 128; k++) {
            float4 h = hp[k], ww = wp[k];
            acc = fmaf(h.x, ww.x, acc); acc = fmaf(h.y, ww.y, acc);
            acc = fmaf(h.z, ww.z, acc); acc = fmaf(h.w, ww.w, acc);
        }
        int r_g = rbase + rt;
        logits[(size_t)r_g * NTAG + tg] = acc + bout[tg];
    }
}

// ---------------- Viterbi (one wave per batch element) ----------------
__global__ void __launch_bounds__(64) viterbi_k(
    const float* __restrict__ logits, const float* __restrict__ trans,
    float* __restrict__ out)
{
    const int b = blockIdx.x, lane = threadIdx.x;
    __shared__ float lgl[LSEQ * NTAG];
    __shared__ unsigned char bp[LSEQ][16];
    __shared__ float pathf[LSEQ];

    {
        const float4* src = (const float4*)(logits + (size_t)b * LSEQ * NTAG);
        float4* dst = (float4*)lgl;
        for (int u = lane; u < (LSEQ * NTAG) / 4; u += 64) dst[u] = src[u];
    }
    float tcol[NTAG];
    if (lane < NTAG) {
#pragma unroll
        for (int i = 0; i < NTAG; i++) tcol[i] = trans[i * NTAG + lane];
    }
    __syncthreads();

    float v = (lane < NTAG) ? lgl[lane] : -1e30f;
    for (int t = 1; t < LSEQ; t++) {
        float best = -1e30f; int bi = 0;
#pragma unroll
        for (int i = 0; i < NTAG; i++) {
            float vi = __shfl(v, i, 64) + tcol[i];
            if (vi > best) { best = vi; bi = i; }   // strict > == first-max
        }
        if (lane < NTAG) {
            v = lgl[t * NTAG + lane] + best;
            bp[t][lane] = (unsigned char)bi;
        }
    }
    float bestv = -1e30f; int bestj = 0;
#pragma unroll
    for (int j = 0; j < NTAG; j++) {
        float vj = __shfl(v, j, 64);
        if (vj > bestv) { bestv = vj; bestj = j; }
    }
    if (lane == 0) {
        out[b] = bestv;
        int st = bestj;
        pathf[LSEQ - 1] = (float)st;
        for (int t = LSEQ - 1; t >= 1; t--) { st = bp[t][st]; pathf[t - 1] = (float)st; }
    }
    __syncthreads();
    for (int t = lane; t < LSEQ; t += 64)
        out[BATCH + (size_t)b * LSEQ + t] = pathf[t];
}

// ---------------- host ----------------
extern "C" void kernel_launch(void* const* d_in, const int* in_sizes, int n_in,
                              void* d_out, int out_size, void* d_ws, size_t ws_size,
                              hipStream_t stream)
{
    (void)in_sizes; (void)n_in; (void)out_size;
    const int*   sent  = (const int*)  d_in[0];
    const float* emb   = (const float*)d_in[1];
    const float* Wihf  = (const float*)d_in[2];
    const float* Whhf  = (const float*)d_in[3];
    const float* bf    = (const float*)d_in[4];
    const float* Wihb  = (const float*)d_in[5];
    const float* Whhb  = (const float*)d_in[6];
    const float* bb    = (const float*)d_in[7];
    const float* Wout  = (const float*)d_in[8];
    const float* bout  = (const float*)d_in[9];
    const float* trans = (const float*)d_in[10];
    const float* h0    = (const float*)d_in[11];
    const float* c0    = (const float*)d_in[12];
    float* out = (float*)d_out;

    // ws (floats): Gin[CT*131072] | hs[16777216] | cbuf[32768] | logits[360448]
    const size_t fixed = 16777216ull + 32768ull + 360448ull;
    int CT = LSEQ;
    while (CT > 8 && ((size_t)CT * 131072ull + fixed) * 4ull > ws_size) CT >>= 1;

    float* ws = (float*)d_ws;
    size_t off = 0;
    float* Gin  = ws + off; off += (size_t)CT * 131072ull;
    float* hs   = ws + off; off += 16777216ull;
    float* cbuf = ws + off; off += 32768ull;
    float* lgts = ws + off; off += 360448ull;

    const int nch = LSEQ / CT;
    for (int c = 0; c < nch; c++) {
        int t0 = c * CT;
        hipLaunchKernelGGL(gemm_in, dim3(CT / 2, 8, 2), dim3(256), 0, stream,
                           sent, emb, Wihf, bf, Wihb, bb, Gin, t0, CT);
        hipLaunchKernelGGL(lstm_rec, dim3(128), dim3(1024), 0, stream,
                           Gin, Whhf, Whhb, h0, c0, hs, cbuf, t0, CT);
    }
    hipLaunchKernelGGL(logits_k, dim3((BATCH * LSEQ) / 16), dim3(256), 0, stream,
                       hs, Wout, bout, lgts);
    hipLaunchKernelGGL(viterbi_k, dim3(BATCH), dim3(64), 0, stream,
                       lgts, trans, out);
}

// Round 7
// 3933.036 us; speedup vs baseline: 2.7539x; 2.7539x over previous
//
#include <hip/hip_runtime.h>
#include <cstdint>
#include <cstddef>
#include <cstring>

#define LSEQ 512
#define BATCH 64
#define DIM 256
#define HID 256
#define NTAG 11

// ---------------- init: zero group-barrier flags ----------------
__global__ void init_ctr(unsigned int* __restrict__ ctr) {
    for (int i = threadIdx.x; i < 1024; i += 256) ctr[i] = 0u;
}

// ---------------- input GEMM (+embedding gather, +bias) ----------------
// Gin layout: [dir][t_local][b][pos] with, for gate-row n (q=n>>8, e=n&255):
//   pos = (e>>5)*128 + ((e>>4)&1)*64 + (e&15)*4 + q
// == lstm_rec's  w*128 + (tid&127)  ordering => each wave reads 256B
// contiguous per batch per step.
__global__ void __launch_bounds__(256) gemm_in(
    const int* __restrict__ sent, const float* __restrict__ emb,
    const float* __restrict__ Wf, const float* __restrict__ bf,
    const float* __restrict__ Wb, const float* __restrict__ bb,
    float* __restrict__ Gin, int t0, int CT)
{
    const int mt = blockIdx.x, nt = blockIdx.y, dir = blockIdx.z;
    const float* __restrict__ W    = dir ? Wb : Wf;
    const float* __restrict__ bias = dir ? bb : bf;
    const int tid = threadIdx.x;
    const int tx = tid & 15, ty = tid >> 4;

    __shared__ float As[128][36];
    __shared__ float Bs[128][36];

    const float* arow[4];
    const float* brow[4];
#pragma unroll
    for (int j = 0; j < 4; j++) {
        int v  = j * 256 + tid;
        int mi = v >> 3;
        int m_g = mt * 128 + mi;
        int b = m_g & 63, tl = m_g >> 6;
        int tg = t0 + tl;
        int tt = dir ? (LSEQ - 1 - tg) : tg;
        int tok = sent[b * LSEQ + tt];
        arow[j] = emb + (size_t)tok * DIM;
        brow[j] = W + (size_t)(nt * 128 + mi) * DIM;
    }

    float acc[8][8];
#pragma unroll
    for (int i = 0; i < 8; i++)
#pragma unroll
        for (int j = 0; j < 8; j++) acc[i][j] = 0.f;

    for (int ki = 0; ki < 8; ki++) {
        const int k0 = ki * 32;
        __syncthreads();
#pragma unroll
        for (int j = 0; j < 4; j++) {
            int v  = j * 256 + tid;
            int mi = v >> 3, k4 = v & 7;
            float4 av = *(const float4*)(arow[j] + k0 + k4 * 4);
            float4 bv = *(const float4*)(brow[j] + k0 + k4 * 4);
            *(float4*)&As[mi][k4 * 4] = av;
            *(float4*)&Bs[mi][k4 * 4] = bv;
        }
        __syncthreads();
#pragma unroll
        for (int k = 0; k < 32; k++) {
            float a[8], bv[8];
#pragma unroll
            for (int i = 0; i < 8; i++) a[i] = As[ty + 16 * i][k];
#pragma unroll
            for (int j = 0; j < 8; j++) bv[j] = Bs[tx + 16 * j][k];
#pragma unroll
            for (int i = 0; i < 8; i++)
#pragma unroll
                for (int j = 0; j < 8; j++) acc[i][j] = fmaf(a[i], bv[j], acc[i][j]);
        }
    }
#pragma unroll
    for (int i = 0; i < 8; i++) {
        int m_g = mt * 128 + ty + 16 * i;
        int b = m_g & 63, tl = m_g >> 6;
        size_t base = ((size_t)(dir * CT + tl) * 64 + b) * 1024;
#pragma unroll
        for (int j = 0; j < 8; j++) {
            int n = nt * 128 + tx + 16 * j;
            int q = n >> 8, e = n & 255;
            int pos = ((e >> 5) << 7) + (((e >> 4) & 1) << 6) + ((e & 15) << 2) + q;
            Gin[base + pos] = acc[i][j] + bias[n];
        }
    }
}

// ---------------- persistent bidirectional LSTM recurrence ----------------
// 256 WGs (256 threads) = 32 groups x 8 WGs; group g = {wg : wg&31==g}.
// Group g: dir=g>>4, batches [4*(g&15), +4). Member w owns hidden elems
// [32w, 32w+32). Thread (wave=tid>>6 -> bp=wave>>1, half=wave&1; lane=4j+q)
// owns FULL gate-row q*256 + 32w + 16*half + j (64 float4 = 256 weight
// VGPRs; legal ONLY at 256 threads x 1 wave/SIMD) for 2 batches bA,bB.
// => no k-split reduction, no partial-sum LDS, 2 syncthreads/step.
// Cross-WG h exchange: agent-scope atomics on hbuf (MALL), per-WG flag
// stores; consumers poll only their slice's producer flag.
__global__ void __launch_bounds__(256, 1) lstm_rec(
    const float* __restrict__ Gin,
    const float* __restrict__ Whh_f, const float* __restrict__ Whh_b,
    const float* __restrict__ h0, const float* __restrict__ c0,
    float* __restrict__ hs, float* __restrict__ hbuf, float* __restrict__ cbuf,
    unsigned int* __restrict__ ctr, int t0, int CT)
{
    const int wg = blockIdx.x;
    const int w = wg >> 5, g = wg & 31;
    const int dir   = g >> 4;
    const int bbase = (g & 15) << 2;
    const int tid = threadIdx.x;
    const int wave = tid >> 6, lane = tid & 63;
    const int bp = wave >> 1, half = wave & 1;
    const int j = lane >> 2, q = lane & 3;
    const int e = (w << 5) + (half << 4) + j;        // hidden elem in [0,256)
    const int row = (q << 8) + e;                    // gate row in [0,1024)
    const int bA = bbase + (bp << 1), bB = bA + 1;
    const float* __restrict__ Whh = dir ? Whh_b : Whh_f;

    float4 wreg[64];                                 // full W_hh row: 256 VGPRs
    {
        const float4* wp = (const float4*)(Whh + (size_t)row * HID);
#pragma unroll
        for (int i = 0; i < 64; i++) wreg[i] = wp[i];
    }

    __shared__ float4 Hl[4][64];   // staged h(t-1) for 4 batches (broadcast reads)

    float cA, cB;
    {
        const float* csrc = (t0 == 0) ? c0 : cbuf;
        cA = csrc[((size_t)dir * BATCH + bA) * HID + e];
        cB = csrc[((size_t)dir * BATCH + bB) * HID + e];
    }

    unsigned int* flags = ctr + g * 32;
    const int sb = tid >> 6, k4 = tid & 63;
    const unsigned int* myflag = flags + (k4 >> 3);

    const float* __restrict__ gp =
        Gin + ((size_t)(dir * CT) * 64 + bA) * 1024 + w * 128 + (tid & 127);
    float gin0 = gp[0];
    float gin1 = gp[1024];

    for (int t = t0; t < t0 + CT; t++) {
        // ---- poll producer flag, stage h(t-1) via agent 8B loads ----
        {
            if (t > 0) {
                const unsigned int tgt = (unsigned int)t;
                while (__hip_atomic_load(myflag, __ATOMIC_RELAXED,
                                         __HIP_MEMORY_SCOPE_AGENT) < tgt)
                    __builtin_amdgcn_s_sleep(1);
            }
            const float* hsrc = (t == 0)
                ? (h0 + (size_t)dir * BATCH * HID)
                : (hbuf + ((size_t)((t - 1) & 1) * 2 + dir) * BATCH * HID);
            const float* hp = hsrc + (size_t)(bbase + sb) * HID + k4 * 4;
            unsigned long long u0 = __hip_atomic_load(
                (const unsigned long long*)hp, __ATOMIC_RELAXED,
                __HIP_MEMORY_SCOPE_AGENT);
            unsigned long long u1 = __hip_atomic_load(
                (const unsigned long long*)(hp + 2), __ATOMIC_RELAXED,
                __HIP_MEMORY_SCOPE_AGENT);
            float4 hv;
            memcpy(&hv.x, &u0, 8);
            memcpy(&hv.z, &u1, 8);
            Hl[sb][k4] = hv;
        }
        __syncthreads();

        // prefetch Gin for t+1
        int tln = t + 1 - t0; if (tln >= CT) tln = CT - 1;
        const float gn0 = gp[(size_t)tln * 65536];
        const float gn1 = gp[(size_t)tln * 65536 + 1024];

        // ---- GEMV: full row x 2 batches (h via LDS broadcast) ----
        float pA = 0.f, pB = 0.f;
        const float4* hpa = &Hl[bp << 1][0];
        const float4* hpb = &Hl[(bp << 1) + 1][0];
#pragma unroll
        for (int i = 0; i < 64; i++) {
            const float4 wv = wreg[i];
            const float4 ha = hpa[i];
            pA = fmaf(wv.x, ha.x, pA); pA = fmaf(wv.y, ha.y, pA);
            pA = fmaf(wv.z, ha.z, pA); pA = fmaf(wv.w, ha.w, pA);
            const float4 hb = hpb[i];
            pB = fmaf(wv.x, hb.x, pB); pB = fmaf(wv.y, hb.y, pB);
            pB = fmaf(wv.z, hb.z, pB); pB = fmaf(wv.w, hb.w, pB);
        }
        const float vA = pA + gin0;
        const float vB = pB + gin1;
        gin0 = gn0; gin1 = gn1;

        // ---- quad shfl gate gather + activations (redundant x4 lanes) ----
        const int qb = lane & 0x3c;
        const float giA = __shfl(vA, qb + 0, 64);
        const float gfA = __shfl(vA, qb + 1, 64);
        const float ggA = __shfl(vA, qb + 2, 64);
        const float goA = __shfl(vA, qb + 3, 64);
        const float giB = __shfl(vB, qb + 0, 64);
        const float gfB = __shfl(vB, qb + 1, 64);
        const float ggB = __shfl(vB, qb + 2, 64);
        const float goB = __shfl(vB, qb + 3, 64);

        cA = (1.f / (1.f + expf(-gfA))) * cA
           + (1.f / (1.f + expf(-giA))) * tanhf(ggA);
        const float hA = (1.f / (1.f + expf(-goA))) * tanhf(cA);
        cB = (1.f / (1.f + expf(-gfB))) * cB
           + (1.f / (1.f + expf(-giB))) * tanhf(ggB);
        const float hB = (1.f / (1.f + expf(-goB))) * tanhf(cB);

        if (q == 0) {
            const int t_orig = dir ? (LSEQ - 1 - t) : t;
            float* hb_w = hbuf + ((size_t)(t & 1) * 2 + dir) * BATCH * HID;
            __hip_atomic_store(&hb_w[(size_t)bA * HID + e], hA,
                               __ATOMIC_RELAXED, __HIP_MEMORY_SCOPE_AGENT);
            __hip_atomic_store(&hb_w[(size_t)bB * HID + e], hB,
                               __ATOMIC_RELAXED, __HIP_MEMORY_SCOPE_AGENT);
            hs[((size_t)(dir * LSEQ + t_orig) * BATCH + bA) * HID + e] = hA;
            hs[((size_t)(dir * LSEQ + t_orig) * BATCH + bB) * HID + e] = hB;
        }
        __syncthreads();   // drains all waves' stores (vmcnt0) before flag
        if (tid == 0)
            __hip_atomic_store(&flags[w], (unsigned int)(t + 1),
                               __ATOMIC_RELAXED, __HIP_MEMORY_SCOPE_AGENT);
    }
    if (q == 0) {
        cbuf[((size_t)dir * BATCH + bA) * HID + e] = cA;
        cbuf[((size_t)dir * BATCH + bB) * HID + e] = cB;
    }
}

// ---------------- output projection: logits[b][t][11] ----------------
__global__ void __launch_bounds__(256) logits_k(
    const float* __restrict__ hs, const float* __restrict__ Wout,
    const float* __restrict__ bout, float* __restrict__ logits)
{
    const int tid = threadIdx.x;
    const int rt = tid >> 4, tg = tid & 15;
    __shared__ float hrow[16][516];
    __shared__ float Wl[NTAG][516];
    const int rbase = blockIdx.x * 16;

#pragma unroll
    for (int i = 0; i < 8; i++) {
        int u  = tid + i * 256;
        int rr = u >> 7, c4 = u & 127;
        int r_g = rbase + rr;
        int b = r_g >> 9, t = r_g & 511;
        int d = (c4 >= 64) ? 1 : 0, k4 = c4 & 63;
        float4 hv = ((const float4*)hs)[(((size_t)d * LSEQ + t) * BATCH + b) * 64 + k4];
        *(float4*)&hrow[rr][c4 * 4] = hv;
    }
    for (int u = tid; u < NTAG * 128; u += 256) {
        int row = u >> 7, c4 = u & 127;
        float4 wv = ((const float4*)Wout)[(size_t)row * 128 + c4];
        *(float4*)&Wl[row][c4 * 4] = wv;
    }
    __syncthreads();

    if (tg < NTAG) {
        const float4* hp = (const float4*)&hrow[rt][0];
        const float4* wp = (const float4*)&Wl[tg][0];
        float acc = 0.f;
#pragma unroll 4
        for (int k = 0; k < 128; k++) {
            float4 h = hp[k], ww = wp[k];
            acc = fmaf(h.x, ww.x, acc); acc = fmaf(h.y, ww.y, acc);
            acc = fmaf(h.z, ww.z, acc); acc = fmaf(h.w, ww.w, acc);
        }
        int r_g = rbase + rt;
        logits[(size_t)r_g * NTAG + tg] = acc + bout[tg];
    }
}

// ---------------- Viterbi (one wave per batch element) ----------------
__global__ void __launch_bounds__(64) viterbi_k(
    const float* __restrict__ logits, const float* __restrict__ trans,
    float* __restrict__ out)
{
    const int b = blockIdx.x, lane = threadIdx.x;
    __shared__ float lgl[LSEQ * NTAG];
    __shared__ unsigned char bp[LSEQ][16];
    __shared__ float pathf[LSEQ];

    {
        const float4* src = (const float4*)(logits + (size_t)b * LSEQ * NTAG);
        float4* dst = (float4*)lgl;
        for (int u = lane; u < (LSEQ * NTAG) / 4; u += 64) dst[u] = src[u];
    }
    float tcol[NTAG];
    if (lane < NTAG) {
#pragma unroll
        for (int i = 0; i < NTAG; i++) tcol[i] = trans[i * NTAG + lane];
    }
    __syncthreads();

    float v = (lane < NTAG) ? lgl[lane] : -1e30f;
    for (int t = 1; t < LSEQ; t++) {
        float best = -1e30f; int bi = 0;
#pragma unroll
        for (int i = 0; i < NTAG; i++) {
            float vi = __shfl(v, i, 64) + tcol[i];
            if (vi > best) { best = vi; bi = i; }   // strict > == first-max
        }
        if (lane < NTAG) {
            v = lgl[t * NTAG + lane] + best;
            bp[t][lane] = (unsigned char)bi;
        }
    }
    float bestv = -1e30f; int bestj = 0;
#pragma unroll
    for (int j = 0; j < NTAG; j++) {
        float vj = __shfl(v, j, 64);
        if (vj > bestv) { bestv = vj; bestj = j; }
    }
    if (lane == 0) {
        out[b] = bestv;
        int st = bestj;
        pathf[LSEQ - 1] = (float)st;
        for (int t = LSEQ - 1; t >= 1; t--) { st = bp[t][st]; pathf[t - 1] = (float)st; }
    }
    __syncthreads();
    for (int t = lane; t < LSEQ; t += 64)
        out[BATCH + (size_t)b * LSEQ + t] = pathf[t];
}

// ---------------- host ----------------
extern "C" void kernel_launch(void* const* d_in, const int* in_sizes, int n_in,
                              void* d_out, int out_size, void* d_ws, size_t ws_size,
                              hipStream_t stream)
{
    (void)in_sizes; (void)n_in; (void)out_size;
    const int*   sent  = (const int*)  d_in[0];
    const float* emb   = (const float*)d_in[1];
    const float* Wihf  = (const float*)d_in[2];
    const float* Whhf  = (const float*)d_in[3];
    const float* bf    = (const float*)d_in[4];
    const float* Wihb  = (const float*)d_in[5];
    const float* Whhb  = (const float*)d_in[6];
    const float* bb    = (const float*)d_in[7];
    const float* Wout  = (const float*)d_in[8];
    const float* bout  = (const float*)d_in[9];
    const float* trans = (const float*)d_in[10];
    const float* h0    = (const float*)d_in[11];
    const float* c0    = (const float*)d_in[12];
    float* out = (float*)d_out;

    const size_t fixed = 16777216ull + 65536ull + 32768ull + 360448ull + 1024ull;
    int CT = LSEQ;
    while (CT > 8 && ((size_t)CT * 131072ull + fixed) * 4ull > ws_size) CT >>= 1;

    float* ws = (float*)d_ws;
    size_t off = 0;
    float* Gin  = ws + off; off += (size_t)CT * 131072ull;
    float* hs   = ws + off; off += 16777216ull;
    float* hbuf = ws + off; off += 65536ull;
    float* cbuf = ws + off; off += 32768ull;
    float* lgts = ws + off; off += 360448ull;
    unsigned int* ctr = (unsigned int*)(ws + off);

    hipLaunchKernelGGL(init_ctr, dim3(1), dim3(256), 0, stream, ctr);

    const int nch = LSEQ / CT;
    for (int c = 0; c < nch; c++) {
        int t0 = c * CT;
        hipLaunchKernelGGL(gemm_in, dim3(CT / 2, 8, 2), dim3(256), 0, stream,
                           sent, emb, Wihf, bf, Wihb, bb, Gin, t0, CT);
        hipLaunchKernelGGL(lstm_rec, dim3(256), dim3(256), 0, stream,
                           Gin, Whhf, Whhb, h0, c0, hs, hbuf, cbuf, ctr, t0, CT);
    }
    hipLaunchKernelGGL(logits_k, dim3((BATCH * LSEQ) / 16), dim3(256), 0, stream,
                       hs, Wout, bout, lgts);
    hipLaunchKernelGGL(viterbi_k, dim3(BATCH), dim3(64), 0, stream,
                       lgts, trans, out);
}

// Round 8
// 2554.639 us; speedup vs baseline: 4.2397x; 1.5396x over previous
//
#include <hip/hip_runtime.h>
#include <cstdint>
#include <cstddef>
#include <cstring>

#define LSEQ 512
#define BATCH 64
#define DIM 256
#define HID 256
#define NTAG 11

// ---------------- input GEMM (+embedding gather, +bias) ----------------
// Gin float layout per (dir,tl): [bg(16)][w(8)][v(4)][jj(8)][q(4)][bi(4)]
// so lstm_rec thread (w, wave=v, lane=jj*8+q*2+s) reads ONE float4 (bi 0..3).
__global__ void __launch_bounds__(256) gemm_in(
    const int* __restrict__ sent, const float* __restrict__ emb,
    const float* __restrict__ Wf, const float* __restrict__ bf,
    const float* __restrict__ Wb, const float* __restrict__ bb,
    float* __restrict__ Gin, int t0, int CT)
{
    const int mt = blockIdx.x, nt = blockIdx.y, dir = blockIdx.z;
    const float* __restrict__ W    = dir ? Wb : Wf;
    const float* __restrict__ bias = dir ? bb : bf;
    const int tid = threadIdx.x;
    const int tx = tid & 15, ty = tid >> 4;

    __shared__ float As[128][36];
    __shared__ float Bs[128][36];

    const float* arow[4];
    const float* brow[4];
#pragma unroll
    for (int j = 0; j < 4; j++) {
        int v  = j * 256 + tid;
        int mi = v >> 3;
        int m_g = mt * 128 + mi;
        int b = m_g & 63, tl = m_g >> 6;
        int tg = t0 + tl;
        int tt = dir ? (LSEQ - 1 - tg) : tg;
        int tok = sent[b * LSEQ + tt];
        arow[j] = emb + (size_t)tok * DIM;
        brow[j] = W + (size_t)(nt * 128 + mi) * DIM;
    }

    float acc[8][8];
#pragma unroll
    for (int i = 0; i < 8; i++)
#pragma unroll
        for (int j = 0; j < 8; j++) acc[i][j] = 0.f;

    for (int ki = 0; ki < 8; ki++) {
        const int k0 = ki * 32;
        __syncthreads();
#pragma unroll
        for (int j = 0; j < 4; j++) {
            int v  = j * 256 + tid;
            int mi = v >> 3, k4 = v & 7;
            float4 av = *(const float4*)(arow[j] + k0 + k4 * 4);
            float4 bv = *(const float4*)(brow[j] + k0 + k4 * 4);
            *(float4*)&As[mi][k4 * 4] = av;
            *(float4*)&Bs[mi][k4 * 4] = bv;
        }
        __syncthreads();
#pragma unroll
        for (int k = 0; k < 32; k++) {
            float a[8], bv[8];
#pragma unroll
            for (int i = 0; i < 8; i++) a[i] = As[ty + 16 * i][k];
#pragma unroll
            for (int j = 0; j < 8; j++) bv[j] = Bs[tx + 16 * j][k];
#pragma unroll
            for (int i = 0; i < 8; i++)
#pragma unroll
                for (int j = 0; j < 8; j++) acc[i][j] = fmaf(a[i], bv[j], acc[i][j]);
        }
    }
#pragma unroll
    for (int i = 0; i < 8; i++) {
        int m_g = mt * 128 + ty + 16 * i;
        int b = m_g & 63, tl = m_g >> 6;
        const int bg = b >> 2, bi = b & 3;
        size_t tbase = ((size_t)(dir * CT + tl) * 16 + bg) * 4096;
#pragma unroll
        for (int j = 0; j < 8; j++) {
            int n = nt * 128 + tx + 16 * j;
            int q = n >> 8, e = n & 255;
            int w = e >> 5, v = (e >> 3) & 3, jj = e & 7;
            Gin[tbase + w * 512 + v * 128 + jj * 16 + q * 4 + bi]
                = acc[i][j] + bias[n];
        }
    }
}

// ---------------- persistent bidirectional LSTM recurrence ----------------
// 256 WGs (256 thr) = 32 groups x 8 members; member w owns elems [32w,+32).
// Thread (wave v, lane = jj*8 + q*2 + s): gate-row q*256 + (32w+8v+jj),
// k-half s -> 32 float4 = 128 weight VGPRs (proven register-resident).
// TAG-IN-DATA exchange: h published as ONE 64-bit agent atomic
// ((t+1)<<32 | h_bits); consumers poll the data word itself until the tag
// matches => single MALL round trip, no flags, no drains, no ordering reqs.
// Slot reuse safe: all-to-all dependency bounds producer/consumer skew <2.
// ONE __syncthreads per step (double-buffered LDS h).
__global__ void __launch_bounds__(256, 1) lstm_rec(
    const float* __restrict__ Gin,
    const float* __restrict__ Whh_f, const float* __restrict__ Whh_b,
    const float* __restrict__ h0, const float* __restrict__ c0,
    float* __restrict__ hs, unsigned long long* __restrict__ htag,
    float* __restrict__ cbuf, int t0, int CT)
{
    const int wg = blockIdx.x;
    const int w = wg >> 5, g = wg & 31;
    const int dir   = g >> 4;
    const int bbase = (g & 15) << 2;
    const int tid = threadIdx.x;
    const int wv = tid >> 6, lane = tid & 63;
    const int jj = lane >> 3, q = (lane >> 1) & 3, s = lane & 1;
    const int ee = (w << 5) + (wv << 3) + jj;      // hidden elem [0,256)
    const int row = (q << 8) + ee;                 // gate row [0,1024)
    const float* __restrict__ Whh = dir ? Whh_b : Whh_f;

    float4 wreg[32];                               // k-half: 128 VGPRs
    {
        const float4* wp = (const float4*)(Whh + (size_t)row * HID + s * 128);
#pragma unroll
        for (int i = 0; i < 32; i++) wreg[i] = wp[i];
    }

    __shared__ float4 Hl[2][4][64];                // [slot][batch][f4]

    // c for (ee, batch bbase+q); s=1 lanes carry a harmless duplicate
    float c = ((t0 == 0) ? c0 : cbuf)[((size_t)dir * BATCH + bbase + q) * HID + ee];

    const int sb = tid >> 6, k4 = tid & 63;        // staging: batch, f4-slot

    // Gin: one float4 per thread per step
    const float4* __restrict__ Gin4 = (const float4*)Gin;
    const size_t gin_thread_off = ((size_t)(dir * CT) * 16 + (bbase >> 2)) * 1024
                                + w * 128 + wv * 32 + jj * 4 + q;
    float4 gv = Gin4[gin_thread_off];              // t_local = 0

    for (int t = t0; t < t0 + CT; t++) {
        const int wslot = t & 1;

        // ---- stage h(t-1): poll tagged data words (single-RT consume) ----
        {
            float4 hv;
            if (t == 0) {
                hv = ((const float4*)(h0 + ((size_t)dir * BATCH + bbase + sb) * HID))[k4];
            } else {
                const unsigned long long* hp =
                    htag + ((((size_t)((t - 1) & 1) * 2 + dir) * BATCH + bbase + sb) * HID
                            + k4 * 4);
                const unsigned int tg = (unsigned int)t;
                unsigned long long u0, u1, u2, u3;
                for (;;) {
                    u0 = __hip_atomic_load(hp + 0, __ATOMIC_RELAXED, __HIP_MEMORY_SCOPE_AGENT);
                    u1 = __hip_atomic_load(hp + 1, __ATOMIC_RELAXED, __HIP_MEMORY_SCOPE_AGENT);
                    u2 = __hip_atomic_load(hp + 2, __ATOMIC_RELAXED, __HIP_MEMORY_SCOPE_AGENT);
                    u3 = __hip_atomic_load(hp + 3, __ATOMIC_RELAXED, __HIP_MEMORY_SCOPE_AGENT);
                    if (((unsigned int)(u0 >> 32) == tg) & ((unsigned int)(u1 >> 32) == tg) &
                        ((unsigned int)(u2 >> 32) == tg) & ((unsigned int)(u3 >> 32) == tg))
                        break;
                    __builtin_amdgcn_s_sleep(1);
                }
                hv.x = __uint_as_float((unsigned int)u0);
                hv.y = __uint_as_float((unsigned int)u1);
                hv.z = __uint_as_float((unsigned int)u2);
                hv.w = __uint_as_float((unsigned int)u3);
            }
            Hl[wslot][sb][k4] = hv;
        }
        __syncthreads();

        // prefetch Gin for t+1
        int tln = t + 1 - t0; if (tln >= CT) tln = CT - 1;
        const float4 gvn = Gin4[gin_thread_off + (size_t)tln * 16384];

        // ---- GEMV: 1 row-half x 4 batches from LDS broadcast ----
        float p0 = 0.f, p1 = 0.f, p2 = 0.f, p3 = 0.f;
        const float4* h0p = &Hl[wslot][0][s * 32];
        const float4* h1p = &Hl[wslot][1][s * 32];
        const float4* h2p = &Hl[wslot][2][s * 32];
        const float4* h3p = &Hl[wslot][3][s * 32];
#pragma unroll
        for (int i = 0; i < 32; i++) {
            const float4 wvv = wreg[i];
            float4 hv;
            hv = h0p[i];
            p0 = fmaf(wvv.x, hv.x, p0); p0 = fmaf(wvv.y, hv.y, p0);
            p0 = fmaf(wvv.z, hv.z, p0); p0 = fmaf(wvv.w, hv.w, p0);
            hv = h1p[i];
            p1 = fmaf(wvv.x, hv.x, p1); p1 = fmaf(wvv.y, hv.y, p1);
            p1 = fmaf(wvv.z, hv.z, p1); p1 = fmaf(wvv.w, hv.w, p1);
            hv = h2p[i];
            p2 = fmaf(wvv.x, hv.x, p2); p2 = fmaf(wvv.y, hv.y, p2);
            p2 = fmaf(wvv.z, hv.z, p2); p2 = fmaf(wvv.w, hv.w, p2);
            hv = h3p[i];
            p3 = fmaf(wvv.x, hv.x, p3); p3 = fmaf(wvv.y, hv.y, p3);
            p3 = fmaf(wvv.z, hv.z, p3); p3 = fmaf(wvv.w, hv.w, p3);
        }
        // pair-sum the two k-halves (lanes s=0/1), add Gin
        const float v0 = p0 + __shfl_xor(p0, 1, 64) + gv.x;
        const float v1 = p1 + __shfl_xor(p1, 1, 64) + gv.y;
        const float v2 = p2 + __shfl_xor(p2, 1, 64) + gv.z;
        const float v3 = p3 + __shfl_xor(p3, 1, 64) + gv.w;
        gv = gvn;

        // ---- gather 4 gates (lanes base+0/2/4/6 hold gates i,f,g,o) ----
        const int base = lane & 0x39;              // jj*8 + s
        const float gi0 = __shfl(v0, base + 0, 64), gf0 = __shfl(v0, base + 2, 64),
                    gg0 = __shfl(v0, base + 4, 64), go0 = __shfl(v0, base + 6, 64);
        const float gi1 = __shfl(v1, base + 0, 64), gf1 = __shfl(v1, base + 2, 64),
                    gg1 = __shfl(v1, base + 4, 64), go1 = __shfl(v1, base + 6, 64);
        const float gi2 = __shfl(v2, base + 0, 64), gf2 = __shfl(v2, base + 2, 64),
                    gg2 = __shfl(v2, base + 4, 64), go2 = __shfl(v2, base + 6, 64);
        const float gi3 = __shfl(v3, base + 0, 64), gf3 = __shfl(v3, base + 2, 64),
                    gg3 = __shfl(v3, base + 4, 64), go3 = __shfl(v3, base + 6, 64);
        // select this lane's batch (bi == q)
        const float gi = (q == 0) ? gi0 : (q == 1) ? gi1 : (q == 2) ? gi2 : gi3;
        const float gf = (q == 0) ? gf0 : (q == 1) ? gf1 : (q == 2) ? gf2 : gf3;
        const float gg = (q == 0) ? gg0 : (q == 1) ? gg1 : (q == 2) ? gg2 : gg3;
        const float go = (q == 0) ? go0 : (q == 1) ? go1 : (q == 2) ? go2 : go3;

        c = (1.f / (1.f + expf(-gf))) * c + (1.f / (1.f + expf(-gi))) * tanhf(gg);
        const float h = (1.f / (1.f + expf(-go))) * tanhf(c);

        if (s == 0) {
            const int t_orig = dir ? (LSEQ - 1 - t) : t;
            const unsigned long long pkt =
                ((unsigned long long)(unsigned int)(t + 1) << 32)
                | (unsigned long long)__float_as_uint(h);
            __hip_atomic_store(
                &htag[(((size_t)wslot * 2 + dir) * BATCH + bbase + q) * HID + ee],
                pkt, __ATOMIC_RELAXED, __HIP_MEMORY_SCOPE_AGENT);
            hs[((size_t)(dir * LSEQ + t_orig) * BATCH + bbase + q) * HID + ee] = h;
        }
    }
    if (s == 0)
        cbuf[((size_t)dir * BATCH + bbase + q) * HID + ee] = c;
}

// ---------------- output projection: logits[b][t][11] ----------------
__global__ void __launch_bounds__(256) logits_k(
    const float* __restrict__ hs, const float* __restrict__ Wout,
    const float* __restrict__ bout, float* __restrict__ logits)
{
    const int tid = threadIdx.x;
    const int rt = tid >> 4, tg = tid & 15;
    __shared__ float hrow[16][516];
    __shared__ float Wl[NTAG][516];
    const int rbase = blockIdx.x * 16;

#pragma unroll
    for (int i = 0; i < 8; i++) {
        int u  = tid + i * 256;
        int rr = u >> 7, c4 = u & 127;
        int r_g = rbase + rr;
        int b = r_g >> 9, t = r_g & 511;
        int d = (c4 >= 64) ? 1 : 0, k4 = c4 & 63;
        float4 hv = ((const float4*)hs)[(((size_t)d * LSEQ + t) * BATCH + b) * 64 + k4];
        *(float4*)&hrow[rr][c4 * 4] = hv;
    }
    for (int u = tid; u < NTAG * 128; u += 256) {
        int row = u >> 7, c4 = u & 127;
        float4 wv = ((const float4*)Wout)[(size_t)row * 128 + c4];
        *(float4*)&Wl[row][c4 * 4] = wv;
    }
    __syncthreads();

    if (tg < NTAG) {
        const float4* hp = (const float4*)&hrow[rt][0];
        const float4* wp = (const float4*)&Wl[tg][0];
        float acc = 0.f;
#pragma unroll 4
        for (int k = 0; k < 128; k++) {
            float4 h = hp[k], ww = wp[k];
            acc = fmaf(h.x, ww.x, acc); acc = fmaf(h.y, ww.y, acc);
            acc = fmaf(h.z, ww.z, acc); acc = fmaf(h.w, ww.w, acc);
        }
        int r_g = rbase + rt;
        logits[(size_t)r_g * NTAG + tg] = acc + bout[tg];
    }
}

// ---------------- Viterbi (one wave per batch element) ----------------
__global__ void __launch_bounds__(64) viterbi_k(
    const float* __restrict__ logits, const float* __restrict__ trans,
    float* __restrict__ out)
{
    const int b = blockIdx.x, lane = threadIdx.x;
    __shared__ float lgl[LSEQ * NTAG];
    __shared__ unsigned char bp[LSEQ][16];
    __shared__ float pathf[LSEQ];

    {
        const float4* src = (const float4*)(logits + (size_t)b * LSEQ * NTAG);
        float4* dst = (float4*)lgl;
        for (int u = lane; u < (LSEQ * NTAG) / 4; u += 64) dst[u] = src[u];
    }
    float tcol[NTAG];
    if (lane < NTAG) {
#pragma unroll
        for (int i = 0; i < NTAG; i++) tcol[i] = trans[i * NTAG + lane];
    }
    __syncthreads();

    float v = (lane < NTAG) ? lgl[lane] : -1e30f;
    for (int t = 1; t < LSEQ; t++) {
        float best = -1e30f; int bi = 0;
#pragma unroll
        for (int i = 0; i < NTAG; i++) {
            float vi = __shfl(v, i, 64) + tcol[i];
            if (vi > best) { best = vi; bi = i; }   // strict > == first-max
        }
        if (lane < NTAG) {
            v = lgl[t * NTAG + lane] + best;
            bp[t][lane] = (unsigned char)bi;
        }
    }
    float bestv = -1e30f; int bestj = 0;
#pragma unroll
    for (int j = 0; j < NTAG; j++) {
        float vj = __shfl(v, j, 64);
        if (vj > bestv) { bestv = vj; bestj = j; }
    }
    if (lane == 0) {
        out[b] = bestv;
        int st = bestj;
        pathf[LSEQ - 1] = (float)st;
        for (int t = LSEQ - 1; t >= 1; t--) { st = bp[t][st]; pathf[t - 1] = (float)st; }
    }
    __syncthreads();
    for (int t = lane; t < LSEQ; t += 64)
        out[BATCH + (size_t)b * LSEQ + t] = pathf[t];
}

// ---------------- host ----------------
extern "C" void kernel_launch(void* const* d_in, const int* in_sizes, int n_in,
                              void* d_out, int out_size, void* d_ws, size_t ws_size,
                              hipStream_t stream)
{
    (void)in_sizes; (void)n_in; (void)out_size;
    const int*   sent  = (const int*)  d_in[0];
    const float* emb   = (const float*)d_in[1];
    const float* Wihf  = (const float*)d_in[2];
    const float* Whhf  = (const float*)d_in[3];
    const float* bf    = (const float*)d_in[4];
    const float* Wihb  = (const float*)d_in[5];
    const float* Whhb  = (const float*)d_in[6];
    const float* bb    = (const float*)d_in[7];
    const float* Wout  = (const float*)d_in[8];
    const float* bout  = (const float*)d_in[9];
    const float* trans = (const float*)d_in[10];
    const float* h0    = (const float*)d_in[11];
    const float* c0    = (const float*)d_in[12];
    float* out = (float*)d_out;

    // ws (floats): Gin[CT*131072] | hs[16777216] | htag[262144 (=131072 u64)]
    //            | cbuf[32768] | logits[360448]
    const size_t fixed = 16777216ull + 262144ull + 32768ull + 360448ull;
    int CT = LSEQ;
    while (CT > 8 && ((size_t)CT * 131072ull + fixed) * 4ull > ws_size) CT >>= 1;

    float* ws = (float*)d_ws;
    size_t off = 0;
    float* Gin  = ws + off; off += (size_t)CT * 131072ull;
    float* hs   = ws + off; off += 16777216ull;
    unsigned long long* htag = (unsigned long long*)(ws + off); off += 262144ull;
    float* cbuf = ws + off; off += 32768ull;
    float* lgts = ws + off; off += 360448ull;

    const int nch = LSEQ / CT;
    for (int c = 0; c < nch; c++) {
        int t0 = c * CT;
        hipLaunchKernelGGL(gemm_in, dim3(CT / 2, 8, 2), dim3(256), 0, stream,
                           sent, emb, Wihf, bf, Wihb, bb, Gin, t0, CT);
        hipLaunchKernelGGL(lstm_rec, dim3(256), dim3(256), 0, stream,
                           Gin, Whhf, Whhb, h0, c0, hs, htag, cbuf, t0, CT);
    }
    hipLaunchKernelGGL(logits_k, dim3((BATCH * LSEQ) / 16), dim3(256), 0, stream,
                       hs, Wout, bout, lgts);
    hipLaunchKernelGGL(viterbi_k, dim3(BATCH), dim3(64), 0, stream,
                       lgts, trans, out);
}

// Round 9
// 2453.433 us; speedup vs baseline: 4.4146x; 1.0413x over previous
//
#include <hip/hip_runtime.h>
#include <cstdint>
#include <cstddef>
#include <cstring>

#define LSEQ 512
#define BATCH 64
#define DIM 256
#define HID 256
#define NTAG 11

typedef float vf4 __attribute__((ext_vector_type(4)));

// ---------------- input GEMM (+embedding gather, +bias) ----------------
// Gin float layout per (dir,tl): [bg(16)][w(8)][v(4)][jj(8)][q(4)][bi(4)]
// so lstm_rec thread (w, wave=v, lane=jj*8+q*2+s) reads ONE float4 (bi 0..3).
__global__ void __launch_bounds__(256) gemm_in(
    const int* __restrict__ sent, const float* __restrict__ emb,
    const float* __restrict__ Wf, const float* __restrict__ bf,
    const float* __restrict__ Wb, const float* __restrict__ bb,
    float* __restrict__ Gin, int t0, int CT)
{
    const int mt = blockIdx.x, nt = blockIdx.y, dir = blockIdx.z;
    const float* __restrict__ W    = dir ? Wb : Wf;
    const float* __restrict__ bias = dir ? bb : bf;
    const int tid = threadIdx.x;
    const int tx = tid & 15, ty = tid >> 4;

    __shared__ float As[128][36];
    __shared__ float Bs[128][36];

    const float* arow[4];
    const float* brow[4];
#pragma unroll
    for (int j = 0; j < 4; j++) {
        int v  = j * 256 + tid;
        int mi = v >> 3;
        int m_g = mt * 128 + mi;
        int b = m_g & 63, tl = m_g >> 6;
        int tg = t0 + tl;
        int tt = dir ? (LSEQ - 1 - tg) : tg;
        int tok = sent[b * LSEQ + tt];
        arow[j] = emb + (size_t)tok * DIM;
        brow[j] = W + (size_t)(nt * 128 + mi) * DIM;
    }

    float acc[8][8];
#pragma unroll
    for (int i = 0; i < 8; i++)
#pragma unroll
        for (int j = 0; j < 8; j++) acc[i][j] = 0.f;

    for (int ki = 0; ki < 8; ki++) {
        const int k0 = ki * 32;
        __syncthreads();
#pragma unroll
        for (int j = 0; j < 4; j++) {
            int v  = j * 256 + tid;
            int mi = v >> 3, k4 = v & 7;
            float4 av = *(const float4*)(arow[j] + k0 + k4 * 4);
            float4 bv = *(const float4*)(brow[j] + k0 + k4 * 4);
            *(float4*)&As[mi][k4 * 4] = av;
            *(float4*)&Bs[mi][k4 * 4] = bv;
        }
        __syncthreads();
#pragma unroll
        for (int k = 0; k < 32; k++) {
            float a[8], bv[8];
#pragma unroll
            for (int i = 0; i < 8; i++) a[i] = As[ty + 16 * i][k];
#pragma unroll
            for (int j = 0; j < 8; j++) bv[j] = Bs[tx + 16 * j][k];
#pragma unroll
            for (int i = 0; i < 8; i++)
#pragma unroll
                for (int j = 0; j < 8; j++) acc[i][j] = fmaf(a[i], bv[j], acc[i][j]);
        }
    }
#pragma unroll
    for (int i = 0; i < 8; i++) {
        int m_g = mt * 128 + ty + 16 * i;
        int b = m_g & 63, tl = m_g >> 6;
        const int bg = b >> 2, bi = b & 3;
        size_t tbase = ((size_t)(dir * CT + tl) * 16 + bg) * 4096;
#pragma unroll
        for (int j = 0; j < 8; j++) {
            int n = nt * 128 + tx + 16 * j;
            int q = n >> 8, e = n & 255;
            int w = e >> 5, v = (e >> 3) & 3, jj = e & 7;
            Gin[tbase + w * 512 + v * 128 + jj * 16 + q * 4 + bi]
                = acc[i][j] + bias[n];
        }
    }
}

// ---------------- persistent bidirectional LSTM recurrence ----------------
// 256 WGs (256 thr) = 32 groups x 8 members; member w owns elems [32w,+32).
// Thread (wave v, lane = jj*8 + q*2 + s): gate-row q*256 + (32w+8v+jj),
// k-half s -> 32 float4 = 128 weight VGPRs. The empty asm "+v" pin makes
// wreg asm-defined => NOT rematerializable: the allocator must keep it
// register-resident (compiler demoted it at R7/R8, re-streaming 128KB/WG/step
// from L2 — the dominant serial cost).
// TAG-IN-DATA exchange: h published as ONE 64-bit agent atomic
// ((t+1)<<32 | h_bits); consumers poll the data word until the tag matches
// => single MALL round trip, no flags, no drains.
// Gate gather: s-pair shfl_xor(1) + 4x4 butterfly transpose (shfl_xor 2,4)
// — all static swizzle patterns (R8's 16 dynamic bpermutes showed 1.34e8
// LDS bank conflicts; static patterns showed 0 in R4).
__global__ void __launch_bounds__(256, 1) lstm_rec(
    const float* __restrict__ Gin,
    const float* __restrict__ Whh_f, const float* __restrict__ Whh_b,
    const float* __restrict__ h0, const float* __restrict__ c0,
    float* __restrict__ hs, unsigned long long* __restrict__ htag,
    float* __restrict__ cbuf, int t0, int CT)
{
    const int wg = blockIdx.x;
    const int w = wg >> 5, g = wg & 31;
    const int dir   = g >> 4;
    const int bbase = (g & 15) << 2;
    const int tid = threadIdx.x;
    const int wv = tid >> 6, lane = tid & 63;
    const int jj = lane >> 3, q = (lane >> 1) & 3, s = lane & 1;
    const int ee = (w << 5) + (wv << 3) + jj;      // hidden elem [0,256)
    const int row = (q << 8) + ee;                 // gate row [0,1024)
    const float* __restrict__ Whh = dir ? Whh_b : Whh_f;

    vf4 wreg[32];                                  // k-half: 128 VGPRs
    {
        const vf4* wp = (const vf4*)(Whh + (size_t)row * HID + s * 128);
#pragma unroll
        for (int i = 0; i < 32; i++) wreg[i] = wp[i];
    }
    // pin: asm-defined values cannot be rematerialized from memory
#pragma unroll
    for (int i = 0; i < 32; i++) asm volatile("" : "+v"(wreg[i]));

    __shared__ float4 Hl[2][4][64];                // [slot][batch][f4]

    // c for (ee, batch bbase+q); s=1 lanes carry a harmless duplicate
    float c = ((t0 == 0) ? c0 : cbuf)[((size_t)dir * BATCH + bbase + q) * HID + ee];

    const int sb = tid >> 6, k4 = tid & 63;        // staging: batch, f4-slot

    const float4* __restrict__ Gin4 = (const float4*)Gin;
    const size_t gin_thread_off = ((size_t)(dir * CT) * 16 + (bbase >> 2)) * 1024
                                + w * 128 + wv * 32 + jj * 4 + q;
    float4 gv = Gin4[gin_thread_off];              // t_local = 0

    const bool qb0 = (lane & 2) != 0;              // q bit0 (lane bit1)
    const bool qb1 = (lane & 4) != 0;              // q bit1 (lane bit2)

    for (int t = t0; t < t0 + CT; t++) {
        const int wslot = t & 1;

        // ---- stage h(t-1): poll tagged data words (single-RT consume) ----
        {
            float4 hv;
            if (t == 0) {
                hv = ((const float4*)(h0 + ((size_t)dir * BATCH + bbase + sb) * HID))[k4];
            } else {
                const unsigned long long* hp =
                    htag + ((((size_t)((t - 1) & 1) * 2 + dir) * BATCH + bbase + sb) * HID
                            + k4 * 4);
                const unsigned int tg = (unsigned int)t;
                unsigned long long u0, u1, u2, u3;
                for (;;) {
                    u0 = __hip_atomic_load(hp + 0, __ATOMIC_RELAXED, __HIP_MEMORY_SCOPE_AGENT);
                    u1 = __hip_atomic_load(hp + 1, __ATOMIC_RELAXED, __HIP_MEMORY_SCOPE_AGENT);
                    u2 = __hip_atomic_load(hp + 2, __ATOMIC_RELAXED, __HIP_MEMORY_SCOPE_AGENT);
                    u3 = __hip_atomic_load(hp + 3, __ATOMIC_RELAXED, __HIP_MEMORY_SCOPE_AGENT);
                    if (((unsigned int)(u0 >> 32) == tg) & ((unsigned int)(u1 >> 32) == tg) &
                        ((unsigned int)(u2 >> 32) == tg) & ((unsigned int)(u3 >> 32) == tg))
                        break;
                    __builtin_amdgcn_s_sleep(1);
                }
                hv.x = __uint_as_float((unsigned int)u0);
                hv.y = __uint_as_float((unsigned int)u1);
                hv.z = __uint_as_float((unsigned int)u2);
                hv.w = __uint_as_float((unsigned int)u3);
            }
            Hl[wslot][sb][k4] = hv;
        }
        __syncthreads();

        // prefetch Gin for t+1
        int tln = t + 1 - t0; if (tln >= CT) tln = CT - 1;
        const float4 gvn = Gin4[gin_thread_off + (size_t)tln * 16384];

        // ---- GEMV: 1 row-half x 4 batches from LDS broadcast ----
        float p0 = 0.f, p1 = 0.f, p2 = 0.f, p3 = 0.f;
        const float4* h0p = &Hl[wslot][0][s * 32];
        const float4* h1p = &Hl[wslot][1][s * 32];
        const float4* h2p = &Hl[wslot][2][s * 32];
        const float4* h3p = &Hl[wslot][3][s * 32];
#pragma unroll
        for (int i = 0; i < 32; i++) {
            const vf4 wvv = wreg[i];
            float4 hv;
            hv = h0p[i];
            p0 = fmaf(wvv[0], hv.x, p0); p0 = fmaf(wvv[1], hv.y, p0);
            p0 = fmaf(wvv[2], hv.z, p0); p0 = fmaf(wvv[3], hv.w, p0);
            hv = h1p[i];
            p1 = fmaf(wvv[0], hv.x, p1); p1 = fmaf(wvv[1], hv.y, p1);
            p1 = fmaf(wvv[2], hv.z, p1); p1 = fmaf(wvv[3], hv.w, p1);
            hv = h2p[i];
            p2 = fmaf(wvv[0], hv.x, p2); p2 = fmaf(wvv[1], hv.y, p2);
            p2 = fmaf(wvv[2], hv.z, p2); p2 = fmaf(wvv[3], hv.w, p2);
            hv = h3p[i];
            p3 = fmaf(wvv[0], hv.x, p3); p3 = fmaf(wvv[1], hv.y, p3);
            p3 = fmaf(wvv[2], hv.z, p3); p3 = fmaf(wvv[3], hv.w, p3);
        }
        // pair-sum the two k-halves (lanes s=0/1), add Gin
        float a0 = p0 + __shfl_xor(p0, 1, 64) + gv.x;   // batch 0
        float a1 = p1 + __shfl_xor(p1, 1, 64) + gv.y;   // batch 1
        float a2 = p2 + __shfl_xor(p2, 1, 64) + gv.z;   // batch 2
        float a3 = p3 + __shfl_xor(p3, 1, 64) + gv.w;   // batch 3
        gv = gvn;

        // ---- 4x4 transpose across q-quad (static butterflies) ----
        // stage 1: exchange across q-bit0 (xor mask 2), slot pairs {0,1},{2,3}
        {
            float s0 = qb0 ? a0 : a1;
            float s1 = qb0 ? a2 : a3;
            float r0 = __shfl_xor(s0, 2, 64);
            float r1 = __shfl_xor(s1, 2, 64);
            if (qb0) { a0 = r0; a2 = r1; } else { a1 = r0; a3 = r1; }
        }
        // stage 2: exchange across q-bit1 (xor mask 4), slot pairs {0,2},{1,3}
        {
            float s0 = qb1 ? a0 : a2;
            float s1 = qb1 ? a1 : a3;
            float r0 = __shfl_xor(s0, 4, 64);
            float r1 = __shfl_xor(s1, 4, 64);
            if (qb1) { a0 = r0; a1 = r1; } else { a2 = r0; a3 = r1; }
        }
        // now a0..a3 = preacts (i,f,g,o) of (elem ee, batch bbase+q)

        c = (1.f / (1.f + expf(-a1))) * c + (1.f / (1.f + expf(-a0))) * tanhf(a2);
        const float h = (1.f / (1.f + expf(-a3))) * tanhf(c);

        if (s == 0) {
            const int t_orig = dir ? (LSEQ - 1 - t) : t;
            const unsigned long long pkt =
                ((unsigned long long)(unsigned int)(t + 1) << 32)
                | (unsigned long long)__float_as_uint(h);
            __hip_atomic_store(
                &htag[(((size_t)wslot * 2 + dir) * BATCH + bbase + q) * HID + ee],
                pkt, __ATOMIC_RELAXED, __HIP_MEMORY_SCOPE_AGENT);
            hs[((size_t)(dir * LSEQ + t_orig) * BATCH + bbase + q) * HID + ee] = h;
        }
    }
    if (s == 0)
        cbuf[((size_t)dir * BATCH + bbase + q) * HID + ee] = c;
}

// ---------------- output projection: logits[b][t][11] ----------------
__global__ void __launch_bounds__(256) logits_k(
    const float* __restrict__ hs, const float* __restrict__ Wout,
    const float* __restrict__ bout, float* __restrict__ logits)
{
    const int tid = threadIdx.x;
    const int rt = tid >> 4, tg = tid & 15;
    __shared__ float hrow[16][516];
    __shared__ float Wl[NTAG][516];
    const int rbase = blockIdx.x * 16;

#pragma unroll
    for (int i = 0; i < 8; i++) {
        int u  = tid + i * 256;
        int rr = u >> 7, c4 = u & 127;
        int r_g = rbase + rr;
        int b = r_g >> 9, t = r_g & 511;
        int d = (c4 >= 64) ? 1 : 0, k4 = c4 & 63;
        float4 hv = ((const float4*)hs)[(((size_t)d * LSEQ + t) * BATCH + b) * 64 + k4];
        *(float4*)&hrow[rr][c4 * 4] = hv;
    }
    for (int u = tid; u < NTAG * 128; u += 256) {
        int row = u >> 7, c4 = u & 127;
        float4 wv = ((const float4*)Wout)[(size_t)row * 128 + c4];
        *(float4*)&Wl[row][c4 * 4] = wv;
    }
    __syncthreads();

    if (tg < NTAG) {
        const float4* hp = (const float4*)&hrow[rt][0];
        const float4* wp = (const float4*)&Wl[tg][0];
        float acc = 0.f;
#pragma unroll 4
        for (int k = 0; k < 128; k++) {
            float4 h = hp[k], ww = wp[k];
            acc = fmaf(h.x, ww.x, acc); acc = fmaf(h.y, ww.y, acc);
            acc = fmaf(h.z, ww.z, acc); acc = fmaf(h.w, ww.w, acc);
        }
        int r_g = rbase + rt;
        logits[(size_t)r_g * NTAG + tg] = acc + bout[tg];
    }
}

// ---------------- Viterbi (one wave per batch element) ----------------
__global__ void __launch_bounds__(64) viterbi_k(
    const float* __restrict__ logits, const float* __restrict__ trans,
    float* __restrict__ out)
{
    const int b = blockIdx.x, lane = threadIdx.x;
    __shared__ float lgl[LSEQ * NTAG];
    __shared__ unsigned char bp[LSEQ][16];
    __shared__ float pathf[LSEQ];

    {
        const float4* src = (const float4*)(logits + (size_t)b * LSEQ * NTAG);
        float4* dst = (float4*)lgl;
        for (int u = lane; u < (LSEQ * NTAG) / 4; u += 64) dst[u] = src[u];
    }
    float tcol[NTAG];
    if (lane < NTAG) {
#pragma unroll
        for (int i = 0; i < NTAG; i++) tcol[i] = trans[i * NTAG + lane];
    }
    __syncthreads();

    float v = (lane < NTAG) ? lgl[lane] : -1e30f;
    for (int t = 1; t < LSEQ; t++) {
        float best = -1e30f; int bi = 0;
#pragma unroll
        for (int i = 0; i < NTAG; i++) {
            float vi = __shfl(v, i, 64) + tcol[i];
            if (vi > best) { best = vi; bi = i; }   // strict > == first-max
        }
        if (lane < NTAG) {
            v = lgl[t * NTAG + lane] + best;
            bp[t][lane] = (unsigned char)bi;
        }
    }
    float bestv = -1e30f; int bestj = 0;
#pragma unroll
    for (int j = 0; j < NTAG; j++) {
        float vj = __shfl(v, j, 64);
        if (vj > bestv) { bestv = vj; bestj = j; }
    }
    if (lane == 0) {
        out[b] = bestv;
        int st = bestj;
        pathf[LSEQ - 1] = (float)st;
        for (int t = LSEQ - 1; t >= 1; t--) { st = bp[t][st]; pathf[t - 1] = (float)st; }
    }
    __syncthreads();
    for (int t = lane; t < LSEQ; t += 64)
        out[BATCH + (size_t)b * LSEQ + t] = pathf[t];
}

// ---------------- host ----------------
extern "C" void kernel_launch(void* const* d_in, const int* in_sizes, int n_in,
                              void* d_out, int out_size, void* d_ws, size_t ws_size,
                              hipStream_t stream)
{
    (void)in_sizes; (void)n_in; (void)out_size;
    const int*   sent  = (const int*)  d_in[0];
    const float* emb   = (const float*)d_in[1];
    const float* Wihf  = (const float*)d_in[2];
    const float* Whhf  = (const float*)d_in[3];
    const float* bf    = (const float*)d_in[4];
    const float* Wihb  = (const float*)d_in[5];
    const float* Whhb  = (const float*)d_in[6];
    const float* bb    = (const float*)d_in[7];
    const float* Wout  = (const float*)d_in[8];
    const float* bout  = (const float*)d_in[9];
    const float* trans = (const float*)d_in[10];
    const float* h0    = (const float*)d_in[11];
    const float* c0    = (const float*)d_in[12];
    float* out = (float*)d_out;

    // ws (floats): Gin[CT*131072] | hs[16777216] | htag[262144 (=131072 u64)]
    //            | cbuf[32768] | logits[360448]
    const size_t fixed = 16777216ull + 262144ull + 32768ull + 360448ull;
    int CT = LSEQ;
    while (CT > 8 && ((size_t)CT * 131072ull + fixed) * 4ull > ws_size) CT >>= 1;

    float* ws = (float*)d_ws;
    size_t off = 0;
    float* Gin  = ws + off; off += (size_t)CT * 131072ull;
    float* hs   = ws + off; off += 16777216ull;
    unsigned long long* htag = (unsigned long long*)(ws + off); off += 262144ull;
    float* cbuf = ws + off; off += 32768ull;
    float* lgts = ws + off; off += 360448ull;

    const int nch = LSEQ / CT;
    for (int c = 0; c < nch; c++) {
        int t0 = c * CT;
        hipLaunchKernelGGL(gemm_in, dim3(CT / 2, 8, 2), dim3(256), 0, stream,
                           sent, emb, Wihf, bf, Wihb, bb, Gin, t0, CT);
        hipLaunchKernelGGL(lstm_rec, dim3(256), dim3(256), 0, stream,
                           Gin, Whhf, Whhb, h0, c0, hs, htag, cbuf, t0, CT);
    }
    hipLaunchKernelGGL(logits_k, dim3((BATCH * LSEQ) / 16), dim3(256), 0, stream,
                       hs, Wout, bout, lgts);
    hipLaunchKernelGGL(viterbi_k, dim3(BATCH), dim3(64), 0, stream,
                       lgts, trans, out);
}